// Round 1
// 7291.808 us; speedup vs baseline: 1.2627x; 1.2627x over previous
//
#include <hip/hip_runtime.h>
#include <math.h>

#define VDIM 8192
#define HDIM 1024
#define BDIM 64
#define TDIM 128
#define H4   4096
#define TCH  16   // staged timesteps per flush

__device__ __forceinline__ float sigf(float x){ return 1.0f/(1.0f + expf(-x)); }

// sortable pack: high 32 = monotone float key, low 32 = V-1-idx so ties pick SMALLEST idx (np first-max)
__device__ __forceinline__ unsigned long long packmax(float v, int vidx){
    unsigned int u = __float_as_uint(v);
    u = (u & 0x80000000u) ? ~u : (u | 0x80000000u);
    return ((unsigned long long)u << 32) | (unsigned int)(VDIM - 1 - vidx);
}

// ---- one-off: gates = h0 @ W_hh.T + b_ih + b_hh  (64 x 4096) ----
__global__ void __launch_bounds__(256)
hh_kernel(const float* __restrict__ h0, const float* __restrict__ W_hh,
          const float* __restrict__ b_ih, const float* __restrict__ b_hh,
          float* __restrict__ gates)
{
    int blk = blockIdx.x;                 // 1024 blocks = 64 b x 16 jt
    int b = blk >> 4;
    int j = (blk & 15)*256 + threadIdx.x;
    const float* hr = h0 + (size_t)b*HDIM;
    const float* wr = W_hh + (size_t)j*HDIM;
    float s = 0.f;
    for (int k = 0; k < HDIM; k += 4){
        float4 hv = *(const float4*)(hr + k);
        float4 wv = *(const float4*)(wr + k);
        s = fmaf(hv.x, wv.x, s); s = fmaf(hv.y, wv.y, s);
        s = fmaf(hv.z, wv.z, s); s = fmaf(hv.w, wv.w, s);
    }
    gates[(size_t)b*H4 + j] = s + b_ih[j] + b_hh[j];
}

// ---- one-off: t=0 cell from gates (c_prev = 0) ----
__global__ void __launch_bounds__(256)
cell0_kernel(const float* __restrict__ gates, float* __restrict__ cbuf,
             float* __restrict__ hbuf)
{
    int b = blockIdx.x, u = threadIdx.x*4;
    const float* gb = gates + (size_t)b*H4;
    float4 gi = *(const float4*)(gb + u);
    float4 gf = *(const float4*)(gb + 1024 + u);
    float4 gg = *(const float4*)(gb + 2048 + u);
    float4 go = *(const float4*)(gb + 3072 + u);
    (void)gf;
    float4 c4, h4;
    c4.x = sigf(gi.x)*tanhf(gg.x); c4.y = sigf(gi.y)*tanhf(gg.y);
    c4.z = sigf(gi.z)*tanhf(gg.z); c4.w = sigf(gi.w)*tanhf(gg.w);
    h4.x = sigf(go.x)*tanhf(c4.x); h4.y = sigf(go.y)*tanhf(c4.y);
    h4.z = sigf(go.z)*tanhf(c4.z); h4.w = sigf(go.w)*tanhf(c4.w);
    *(float4*)(cbuf + (size_t)b*HDIM + u) = c4;
    *(float4*)(hbuf + (size_t)b*HDIM + u) = h4;
}

// ---- one-off: W_ihT[v][j] = W_ih[j][v]  (8192 x 4096) ----
__global__ void __launch_bounds__(256)
tr_kernel(const float* __restrict__ W, float* __restrict__ WT)
{
    __shared__ float tile[64][65];
    const int jb = blockIdx.x * 64;   // j tile base (0..4095)
    const int vb = blockIdx.y * 64;   // v tile base (0..8191)
    const int tx = threadIdx.x & 63;
    const int ty = threadIdx.x >> 6;  // 0..3
    #pragma unroll
    for (int k = 0; k < 64; k += 4)
        tile[ty + k][tx] = W[(size_t)(jb + ty + k)*VDIM + vb + tx];
    __syncthreads();
    #pragma unroll
    for (int k = 0; k < 64; k += 4)
        WT[(size_t)(vb + ty + k)*H4 + jb + tx] = tile[tx][ty + k];
}

// ---- per step: logits = h @ W_fc.T + b_fc ; stage or strided-write; pmax[b][blk] ----
// 256 blocks x 512 threads. Block tile: 64b x 32v, full K=1024.
// Thread (g = tid>>5 in [0,16), s = tid&31): 8b x 8v tile, K-range [g*64, g*64+64).
__global__ void __launch_bounds__(512, 2)
fc_kernel(const float* __restrict__ W_fc, const float* __restrict__ b_fc,
          const float* __restrict__ hbuf, float* __restrict__ out,
          float* __restrict__ stage,   // may be null -> strided direct write
          unsigned long long* __restrict__ pmax, int t)
{
    __shared__ float buf[8*2048];                 // 64 KB reduce buffer
    __shared__ unsigned long long bmax[512];
    const int tid = threadIdx.x;
    const int blk = blockIdx.x;
    const int vbase = blk * 32;
    const int g  = tid >> 5;
    const int s  = tid & 31;
    const int b0 = (s >> 2) * 8;
    const int v0 = (s & 3) * 8;
    const int k0 = g * 64;

    float acc[8][8];
    #pragma unroll
    for (int i=0;i<8;++i){
        #pragma unroll
        for (int j=0;j<8;++j) acc[i][j] = 0.f;
    }

    const float* hb = hbuf + (size_t)b0*HDIM + k0;
    const float* wb = W_fc + (size_t)(vbase + v0)*HDIM + k0;

    #pragma unroll 2
    for (int kc = 0; kc < 16; ++kc){
        float4 h4[8], w4[8];
        #pragma unroll
        for (int i=0;i<8;++i) h4[i] = *(const float4*)(hb + (size_t)i*HDIM + kc*4);
        #pragma unroll
        for (int j=0;j<8;++j) w4[j] = *(const float4*)(wb + (size_t)j*HDIM + kc*4);
        #pragma unroll
        for (int i=0;i<8;++i){
            #pragma unroll
            for (int j=0;j<8;++j){
                acc[i][j] = fmaf(h4[i].x, w4[j].x, acc[i][j]);
                acc[i][j] = fmaf(h4[i].y, w4[j].y, acc[i][j]);
                acc[i][j] = fmaf(h4[i].z, w4[j].z, acc[i][j]);
                acc[i][j] = fmaf(h4[i].w, w4[j].w, acc[i][j]);
            }
        }
    }

    // tree-reduce the 16 k-split groups (deterministic order)
    for (int half = 8; half >= 1; half >>= 1){
        if (g >= half && g < 2*half){
            float* bp = buf + (g - half)*2048;
            #pragma unroll
            for (int i=0;i<8;++i)
                #pragma unroll
                for (int j=0;j<8;++j) bp[(b0+i)*32 + v0 + j] = acc[i][j];
        }
        __syncthreads();
        if (g < half){
            const float* bp = buf + g*2048;
            #pragma unroll
            for (int i=0;i<8;++i)
                #pragma unroll
                for (int j=0;j<8;++j) acc[i][j] += bp[(b0+i)*32 + v0 + j];
        }
        __syncthreads();
    }
    if (g == 0){
        #pragma unroll
        for (int i=0;i<8;++i)
            #pragma unroll
            for (int j=0;j<8;++j) buf[(b0+i)*32 + v0 + j] = acc[i][j];
    }
    __syncthreads();

    // epilogue: 512 threads x 4 outputs: b = tid>>3, vv = (tid&7)*4
    {
        int b  = tid >> 3;
        int vv = (tid & 7) * 4;
        float4 r = *(float4*)(buf + b*32 + vv);
        int v = vbase + vv;
        r.x += b_fc[v]; r.y += b_fc[v+1]; r.z += b_fc[v+2]; r.w += b_fc[v+3];
        if (stage){
            // stage[t%16][b][v] : contiguous float4, coalesced-enough (128B bursts)
            *(float4*)(stage + (((size_t)(t & (TCH-1))*BDIM + b)*VDIM + v)) = r;
        } else {
            float* ob = out + ((size_t)b*VDIM + v)*TDIM + t;
            ob[0] = r.x; ob[TDIM] = r.y; ob[2*TDIM] = r.z; ob[3*TDIM] = r.w;
        }
        unsigned long long m  = packmax(r.x, v);
        unsigned long long m2 = packmax(r.y, v+1); if (m2 > m) m = m2;
        m2 = packmax(r.z, v+2); if (m2 > m) m = m2;
        m2 = packmax(r.w, v+3); if (m2 > m) m = m2;
        bmax[tid] = m;
        __syncthreads();
        if (tid < 64){
            unsigned long long mm = bmax[tid*8];
            #pragma unroll
            for (int q=1;q<8;++q){ unsigned long long z = bmax[tid*8+q]; if (z > mm) mm = z; }
            pmax[(size_t)tid*256 + blk] = mm;
        }
    }
}

// ---- flush 16 staged timesteps into out[b][v][t0..t0+15] (full-line writes) ----
__global__ void __launch_bounds__(256)
flush_kernel(const float* __restrict__ stage, float* __restrict__ out, int t0)
{
    const size_t n = (size_t)blockIdx.x*256 + threadIdx.x;  // 0 .. B*V-1
    const int b = (int)(n >> 13);
    const int v = (int)(n & (VDIM-1));
    const size_t st = (size_t)BDIM*VDIM;
    const float* sp = stage + (size_t)b*VDIM + v;
    float* op = out + ((size_t)b*VDIM + v)*TDIM + t0;
    float4 o0, o1, o2, o3;
    o0.x = sp[0*st];  o0.y = sp[1*st];  o0.z = sp[2*st];  o0.w = sp[3*st];
    o1.x = sp[4*st];  o1.y = sp[5*st];  o1.z = sp[6*st];  o1.w = sp[7*st];
    o2.x = sp[8*st];  o2.y = sp[9*st];  o2.z = sp[10*st]; o2.w = sp[11*st];
    o3.x = sp[12*st]; o3.y = sp[13*st]; o3.z = sp[14*st]; o3.w = sp[15*st];
    *(float4*)(op + 0)  = o0;
    *(float4*)(op + 4)  = o1;
    *(float4*)(op + 8)  = o2;
    *(float4*)(op + 12) = o3;
}

// ---- per step: argmax finalize + W_ih column gather + LSTM cell. 64 blocks (one per b). ----
__global__ void __launch_bounds__(256)
cell_kernel(const float* __restrict__ W_ih, const float* __restrict__ W_ihT,
            float* __restrict__ gates, float* __restrict__ cbuf,
            float* __restrict__ hbuf, const unsigned long long* __restrict__ pmax)
{
    __shared__ float gbuf[H4];
    __shared__ unsigned long long red[256];
    const int b = blockIdx.x, tid = threadIdx.x;

    red[tid] = pmax[(size_t)b*256 + tid];
    __syncthreads();
    for (int st = 128; st; st >>= 1){
        if (tid < st){ if (red[tid+st] > red[tid]) red[tid] = red[tid+st]; }
        __syncthreads();
    }
    const int idx = VDIM - 1 - (int)(unsigned int)(red[0] & 0xffffffffULL);

    float* gb = gates + (size_t)b*H4;
    if (W_ihT){
        const float* row = W_ihT + (size_t)idx*H4;   // coalesced 16 KB row
        #pragma unroll
        for (int q = 0; q < 4; ++q){
            int j4 = q*1024 + tid*4;
            float4 wv = *(const float4*)(row + j4);
            float4 gv = *(const float4*)(gb + j4);
            gv.x += wv.x; gv.y += wv.y; gv.z += wv.z; gv.w += wv.w;
            *(float4*)(gb + j4) = gv;
            *(float4*)(gbuf + j4) = gv;
        }
    } else {
        #pragma unroll
        for (int q = 0; q < 16; ++q){
            int j = q*256 + tid;
            float gv = gb[j] + W_ih[(size_t)j*VDIM + idx];
            gb[j] = gv;
            gbuf[j] = gv;
        }
    }
    __syncthreads();

    int u = tid*4;
    float4 gi = *(float4*)(gbuf + u);
    float4 gf = *(float4*)(gbuf + 1024 + u);
    float4 gg = *(float4*)(gbuf + 2048 + u);
    float4 go = *(float4*)(gbuf + 3072 + u);
    float4 c4 = *(float4*)(cbuf + (size_t)b*HDIM + u);
    c4.x = sigf(gf.x)*c4.x + sigf(gi.x)*tanhf(gg.x);
    c4.y = sigf(gf.y)*c4.y + sigf(gi.y)*tanhf(gg.y);
    c4.z = sigf(gf.z)*c4.z + sigf(gi.z)*tanhf(gg.z);
    c4.w = sigf(gf.w)*c4.w + sigf(gi.w)*tanhf(gg.w);
    float4 h4;
    h4.x = sigf(go.x)*tanhf(c4.x); h4.y = sigf(go.y)*tanhf(c4.y);
    h4.z = sigf(go.z)*tanhf(c4.z); h4.w = sigf(go.w)*tanhf(c4.w);
    *(float4*)(cbuf + (size_t)b*HDIM + u) = c4;
    *(float4*)(hbuf + (size_t)b*HDIM + u) = h4;
}

extern "C" void kernel_launch(void* const* d_in, const int* in_sizes, int n_in,
                              void* d_out, int out_size, void* d_ws, size_t ws_size,
                              hipStream_t stream)
{
    const float* h0   = (const float*)d_in[0];
    const float* W_ih = (const float*)d_in[1];
    const float* W_hh = (const float*)d_in[2];
    const float* b_ih = (const float*)d_in[3];
    const float* b_hh = (const float*)d_in[4];
    const float* W_fc = (const float*)d_in[5];
    const float* b_fc = (const float*)d_in[6];
    float* out = (float*)d_out;

    // ws layout: base (~1.7 MB) [+ stage 32 MB] [+ W_ihT 128 MB]
    float* gates = (float*)d_ws;                               // 64*4096
    float* cbuf  = gates + (size_t)BDIM*H4;                    // 64*1024
    float* hbuf  = cbuf  + (size_t)BDIM*HDIM;                  // 64*1024
    unsigned long long* pmax = (unsigned long long*)(hbuf + (size_t)BDIM*HDIM); // 64*256 u64

    size_t off = (size_t)BDIM*H4*4 + 2*(size_t)BDIM*HDIM*4 + (size_t)BDIM*256*8;
    const size_t STAGE_B = (size_t)TCH*BDIM*VDIM*4;        // 32 MB
    const size_t WT_B    = (size_t)VDIM*H4*4;              // 128 MB
    float* stage = nullptr;
    float* wT    = nullptr;
    if (ws_size >= off + STAGE_B){ stage = (float*)((char*)d_ws + off); off += STAGE_B; }
    if (ws_size >= off + WT_B)   { wT    = (float*)((char*)d_ws + off); off += WT_B; }

    hipLaunchKernelGGL(hh_kernel, dim3(1024), dim3(256), 0, stream,
                       h0, W_hh, b_ih, b_hh, gates);
    hipLaunchKernelGGL(cell0_kernel, dim3(64), dim3(256), 0, stream,
                       gates, cbuf, hbuf);
    if (wT){
        hipLaunchKernelGGL(tr_kernel, dim3(64, 128), dim3(256), 0, stream,
                           W_ih, wT);
    }

    for (int t = 0; t < TDIM; ++t){
        hipLaunchKernelGGL(fc_kernel, dim3(256), dim3(512), 0, stream,
                           W_fc, b_fc, hbuf, out, stage, pmax, t);
        if (stage && (t & (TCH-1)) == (TCH-1)){
            hipLaunchKernelGGL(flush_kernel, dim3(BDIM*VDIM/256), dim3(256), 0, stream,
                               stage, out, t - (TCH-1));
        }
        if (t < TDIM - 1){
            hipLaunchKernelGGL(cell_kernel, dim3(64), dim3(256), 0, stream,
                               W_ih, wT, gates, cbuf, hbuf, pmax);
        }
    }
}